// Round 6
// baseline (279.506 us; speedup 1.0000x reference)
//
#include <hip/hip_runtime.h>
#include <math.h>

// SemiConnectedConv, single fused bf16-MFMA implicit-GEMM kernel.
// out[px, branch] = sum_k patch[px,k] * Wd[k,branch], k = tap*16 + c,
// 26 taps (25 real + 1 zero-weight pad tap aliasing tap 0) x 16 ch = 416 = 13 K-steps.
//
// Block = (batch, band of 7 output rows). LDS = 6-slot ring of padded rows in
// NHWC bf16 ([px][c] 32B units, XOR-swizzled: unit = px*2 + (chalf ^ (px>>2)&1)).
// Per row: threads read next fp32 NCHW row coalesced -> regs (issued right
// after the barrier, consumed next iteration => HBM latency hidden under MFMA),
// convert+pack -> one ds_write_b128. Ring slot written == the one slot not in
// any concurrent reader's set => ONE barrier/row, no extra drain.
// B-fragments (26 x 16B) live in registers for the whole block.

#define HH 224
#define WW 224
#define CIN 16
#define NBR 32
#define HW (HH * WW)
#define KSTEPS 13
#define RROWS 7
#define RING 6
#define UNITS 456            // 16B units per ring slot = 228 px * 2 halves

typedef short short8 __attribute__((ext_vector_type(8)));
typedef float f32x4 __attribute__((ext_vector_type(4)));

static __device__ __forceinline__ unsigned short f2bf(float f) {
    unsigned int u = __float_as_uint(f);
    return (unsigned short)((u + 0x7FFFu + ((u >> 16) & 1u)) >> 16);   // RNE
}

// ---- weights -> B-fragments: short bfrag[KSTEPS][2 nt][64 lane][8] ----
__global__ __launch_bounds__(64)
void prep_wfrag(const float* __restrict__ Wc, short* __restrict__ ws) {
    int t = blockIdx.x * 64 + threadIdx.x;   // 26 blocks x 64
    int lane = t & 63;
    int rest = t >> 6;
    int nt = rest & 1;
    int kstep = rest >> 1;
    int n = lane & 15;
    int bi = nt * 16 + n;
    int kbase = kstep * 32 + (lane >> 4) * 8;
    short8 pack;
    #pragma unroll
    for (int j = 0; j < 8; ++j) {
        int kg = kbase + j;
        float val = 0.0f;
        if (kg < 400) {
            int tap = kg >> 4;
            int c = kg & 15;
            if (((c + bi) & 15) < 8) {
                int jsel = 0;
                for (int cc = 0; cc < c; ++cc) jsel += (((cc + bi) & 15) < 8) ? 1 : 0;
                val = Wc[(bi * 8 + jsel) * 25 + tap];
            }
        }
        pack[j] = (short)f2bf(val);
    }
    *(short8*)(ws + (size_t)t * 8) = pack;
}

__global__ __launch_bounds__(512, 6)
void semiconv_fused(const float* __restrict__ x,
                    const short* __restrict__ wfrag,
                    const float* __restrict__ bc,
                    float* __restrict__ out) {
    __shared__ short ring[RING * UNITS * 8];   // 43776 B

    const int band = blockIdx.x;               // 0..31
    const int b    = blockIdx.y;               // 0..15
    const int h0   = band * RROWS;
    const int tid  = threadIdx.x;
    const int wave = tid >> 6;
    const int lane = tid & 63;

    // ---- staging role: item = (padded col spx, channel-half sh8) ----
    const bool stg = tid < 2 * 228;
    const int  spx = tid >> 1;                 // 0..227
    const int  sh8 = tid & 1;
    const int  sgw = spx - 2;
    const bool gwok = (unsigned)sgw < (unsigned)WW;
    const float* xs = x + ((size_t)(b * CIN + sh8 * 8) * HH) * WW + (gwok ? sgw : 0);
    const int  sunit = spx * 2 + (sh8 ^ ((spx >> 2) & 1));

    float v[8];

#define LD_ROW(pr) do {                                                   \
        int gh_ = (pr) - 2;                                               \
        bool rok_ = (unsigned)gh_ < (unsigned)HH;                         \
        const float* xp_ = xs + (size_t)(rok_ ? gh_ : 0) * WW;            \
        bool ok_ = rok_ && gwok;                                          \
        _Pragma("unroll")                                                 \
        for (int i_ = 0; i_ < 8; ++i_) {                                  \
            float t_ = xp_[(size_t)i_ * HW];                              \
            v[i_] = ok_ ? t_ : 0.0f;                                      \
        }                                                                 \
    } while (0)

#define WR_ROW(pr) do {                                                   \
        int slot_ = (pr) % RING;                                          \
        int4 pk_;                                                         \
        pk_.x = (int)((unsigned)f2bf(v[0]) | ((unsigned)f2bf(v[1]) << 16)); \
        pk_.y = (int)((unsigned)f2bf(v[2]) | ((unsigned)f2bf(v[3]) << 16)); \
        pk_.z = (int)((unsigned)f2bf(v[4]) | ((unsigned)f2bf(v[5]) << 16)); \
        pk_.w = (int)((unsigned)f2bf(v[6]) | ((unsigned)f2bf(v[7]) << 16)); \
        *(int4*)&ring[(slot_ * UNITS + sunit) * 8] = pk_;                 \
    } while (0)

    // ---- compute role ----
    const int m     = lane & 15;
    const int chalf = (lane >> 4) & 1;
    const int half  = lane >> 5;
    const int wbase = wave * 32;               // waves 0..6 cover 224 px
    const int pxm   = wbase + m;

    short8 bf[2 * KSTEPS];                     // all B-fragments in registers
    #pragma unroll
    for (int i = 0; i < 2 * KSTEPS; ++i)
        bf[i] = ((const short8*)wfrag)[i * 64 + lane];

    // ---- prologue: stage padded rows h0..h0+3, then issue loads for h0+4 ----
    #pragma unroll 1
    for (int p = 0; p < 4; ++p) {
        if (stg) { LD_ROW(h0 + p); WR_ROW(h0 + p); }
    }
    if (stg) LD_ROW(h0 + 4);

    // ---- main loop: one output row per iteration, ONE barrier per row ----
    #pragma unroll 1
    for (int r = 0; r < RROWS; ++r) {
        if (stg) WR_ROW(h0 + 4 + r);           // ring slot (h0+4+r)%6: not in any
        __syncthreads();                       //   concurrent reader's slot set
        if (stg && r < RROWS - 1) LD_ROW(h0 + 5 + r);   // in flight during MFMA

        if (wave < 7) {
            int slv[5];
            #pragma unroll
            for (int kh = 0; kh < 5; ++kh) slv[kh] = (h0 + r + kh) % RING;

            f32x4 acc[2][2] = {};
            #pragma unroll
            for (int s = 0; s < KSTEPS; ++s) {
                const int tap0 = 2 * s;
                const int tap1 = (2 * s + 1 < 25) ? (2 * s + 1) : 24;  // pad tap
                const int kh0 = tap0 / 5, kw0 = tap0 % 5;
                const int kh1 = tap1 / 5, kw1 = tap1 % 5;
                const int sl = half ? slv[kh1] : slv[kh0];
                const int px = pxm + (half ? kw1 : kw0);
                const int u0 = (sl * UNITS + px * 2 + (chalf ^ ((px >> 2) & 1))) * 8;
                const short8 a0 = *(const short8*)&ring[u0];
                const short8 a1 = *(const short8*)&ring[u0 + 256];      // px+16
                acc[0][0] = __builtin_amdgcn_mfma_f32_16x16x32_bf16(a0, bf[2*s],   acc[0][0], 0, 0, 0);
                acc[0][1] = __builtin_amdgcn_mfma_f32_16x16x32_bf16(a0, bf[2*s+1], acc[0][1], 0, 0, 0);
                acc[1][0] = __builtin_amdgcn_mfma_f32_16x16x32_bf16(a1, bf[2*s],   acc[1][0], 0, 0, 0);
                acc[1][1] = __builtin_amdgcn_mfma_f32_16x16x32_bf16(a1, bf[2*s+1], acc[1][1], 0, 0, 0);
            }

            // epilogue: D col = branch (lane&15), row = pixel (lane>>4)*4+reg
            const int hrow = h0 + r;
            const int rowm = (lane >> 4) * 4;
            #pragma unroll
            for (int nt = 0; nt < 2; ++nt) {
                const int branch = nt * 16 + m;
                const float bias = bc[branch];
                #pragma unroll
                for (int mt = 0; mt < 2; ++mt) {
                    const int w0c = wbase + mt * 16 + rowm;
                    float4 o;
                    o.x = __builtin_amdgcn_rcpf(1.0f + __expf(-(acc[mt][nt][0] + bias)));
                    o.y = __builtin_amdgcn_rcpf(1.0f + __expf(-(acc[mt][nt][1] + bias)));
                    o.z = __builtin_amdgcn_rcpf(1.0f + __expf(-(acc[mt][nt][2] + bias)));
                    o.w = __builtin_amdgcn_rcpf(1.0f + __expf(-(acc[mt][nt][3] + bias)));
                    *(float4*)(out + (((size_t)b * NBR + branch) * HH + hrow) * WW + w0c) = o;
                }
            }
        }
    }
#undef LD_ROW
#undef WR_ROW
}

extern "C" void kernel_launch(void* const* d_in, const int* in_sizes, int n_in,
                              void* d_out, int out_size, void* d_ws, size_t ws_size,
                              hipStream_t stream) {
    const float* x  = (const float*)d_in[0];
    const float* Wc = (const float*)d_in[1];
    const float* bc = (const float*)d_in[2];
    float* out = (float*)d_out;
    short* wfrag = (short*)d_ws;                   // 26,624 B

    prep_wfrag<<<26, 64, 0, stream>>>(Wc, wfrag);
    semiconv_fused<<<dim3(32, 16), 512, 0, stream>>>(x, wfrag, bc, out);
}

// Round 7
// 180.641 us; speedup vs baseline: 1.5473x; 1.5473x over previous
//
#include <hip/hip_runtime.h>
#include <math.h>

// SemiConnectedConv as dense bf16-MFMA implicit GEMM, 3 kernels (round-5
// structure restored after fused-kernel regression; + 2 rows/block in main):
//  1) prep_wfrag:  weights -> dense zero-padded MFMA B-fragments (26.6 KB ws)
//  2) transpose_x: fp32 NCHW -> bf16 NHWC with 2-px zero halo (26.6 MB ws)
//  3) semiconv_main: block = (batch, 2 output rows): stage 6 contiguous xT
//     rows via global_load_lds (43.8 KB), 13 K-step MFMA per row (26 taps x
//     16 ch; tap 25 = zero-weight pad aliasing tap 24), sigmoid + float4 stores.

#define HH 224
#define WW 224
#define BB 16
#define CIN 16
#define NBR 32
#define PH 228
#define PW 228
#define KSTEPS 13

typedef short short8 __attribute__((ext_vector_type(8)));
typedef float f32x4 __attribute__((ext_vector_type(4)));

static __device__ __forceinline__ unsigned short f2bf(float f) {
    unsigned int u = __float_as_uint(f);
    return (unsigned short)((u + 0x7FFFu + ((u >> 16) & 1u)) >> 16);   // RNE
}

// ---- weights -> B-fragments: short bfrag[KSTEPS][2 nt][64 lane][8] ----
__global__ __launch_bounds__(64)
void prep_wfrag(const float* __restrict__ Wc, short* __restrict__ ws) {
    int t = blockIdx.x * 64 + threadIdx.x;   // 26 blocks x 64
    int lane = t & 63;
    int rest = t >> 6;
    int nt = rest & 1;
    int kstep = rest >> 1;
    int n = lane & 15;
    int bi = nt * 16 + n;
    int kbase = kstep * 32 + (lane >> 4) * 8;
    short8 pack;
    #pragma unroll
    for (int j = 0; j < 8; ++j) {
        int kg = kbase + j;
        float val = 0.0f;
        if (kg < 400) {
            int tap = kg >> 4;
            int c = kg & 15;
            if (((c + bi) & 15) < 8) {
                int jsel = 0;
                for (int cc = 0; cc < c; ++cc) jsel += (((cc + bi) & 15) < 8) ? 1 : 0;
                val = Wc[(bi * 8 + jsel) * 25 + tap];
            }
        }
        pack[j] = (short)f2bf(val);
    }
    *(short8*)(ws + (size_t)t * 8) = pack;
}

// ---- x fp32 NCHW -> xT bf16 [b][ph 228][pw 228][c 16], zero halo ----
__global__ __launch_bounds__(256)
void transpose_x(const float* __restrict__ x, short* __restrict__ xT) {
    const int b = blockIdx.y;
    const int prow = blockIdx.x * 4 + (threadIdx.x >> 6);   // 0..227
    const int t = threadIdx.x & 63;
    const int gh = prow - 2;
    short* dst = xT + ((size_t)b * PH + prow) * (PW * CIN);

    if (t < 56) {
        const int gw = t * 4;                 // -> padded cols 4t+2..4t+5
        unsigned int pk[4][8];
        if ((unsigned)gh < HH) {
            const float* xp = x + (size_t)b * CIN * HH * WW + (size_t)gh * WW + gw;
            #pragma unroll
            for (int w2 = 0; w2 < 8; ++w2) {  // channel pair (2*w2, 2*w2+1)
                float4 v0 = *(const float4*)(xp + (size_t)(2 * w2) * (HH * WW));
                float4 v1 = *(const float4*)(xp + (size_t)(2 * w2 + 1) * (HH * WW));
                const float* f0 = (const float*)&v0;
                const float* f1 = (const float*)&v1;
                #pragma unroll
                for (int p = 0; p < 4; ++p)
                    pk[p][w2] = (unsigned)f2bf(f0[p]) | ((unsigned)f2bf(f1[p]) << 16);
            }
        } else {
            #pragma unroll
            for (int p = 0; p < 4; ++p)
                #pragma unroll
                for (int w2 = 0; w2 < 8; ++w2) pk[p][w2] = 0u;
        }
        #pragma unroll
        for (int p = 0; p < 4; ++p) {
            int4* o = (int4*)(dst + (size_t)(gw + 2 + p) * CIN);
            o[0] = make_int4(pk[p][0], pk[p][1], pk[p][2], pk[p][3]);
            o[1] = make_int4(pk[p][4], pk[p][5], pk[p][6], pk[p][7]);
        }
    } else if (t == 56) {                     // halo cols {0,1} and {226,227}
        int4 z = make_int4(0, 0, 0, 0);
        int4* o0 = (int4*)(dst);
        o0[0] = z; o0[1] = z;
        int4* o1 = (int4*)(dst + 226 * CIN);
        o1[0] = z; o1[1] = z;
    }
}

// ---- main: block = (2 output rows, batch), 7 waves of 32 px x 32 branches --
__global__ __launch_bounds__(448, 4)
void semiconv_main(const short* __restrict__ xT,
                   const short* __restrict__ wfrag,
                   const float* __restrict__ bc,
                   float* __restrict__ out) {
    __shared__ short tile[6 * PW * CIN];      // 43776 B, rows h..h+5 of xT

    const int bidx = blockIdx.x;              // 0..111
    const int b = blockIdx.y;
    const int h = ((bidx & 7) * 14 + (bidx >> 3)) * 2;   // XCD-contiguous bands
    const int tid = threadIdx.x;
    const int wave = tid >> 6;
    const int lane = tid & 63;

    // 6 padded rows h..h+5 are ONE contiguous span: 2736 x 16B chunks
    const short* src0 = xT + ((size_t)b * PH + h) * (PW * CIN);
    #pragma unroll
    for (int i = 0; i < 6; ++i) {
        __builtin_amdgcn_global_load_lds(
            (const __attribute__((address_space(1))) void*)(src0 + (size_t)(tid + i * 448) * 8),
            (__attribute__((address_space(3))) void*)(tile + (wave * 64 + i * 448) * 8),
            16, 0, 0);
    }
    if (tid < 48) {                            // tail chunks 2688..2735
        const int chunk = 2688 + tid;
        *(int4*)(tile + chunk * 8) = *(const int4*)(src0 + (size_t)chunk * 8);
    }
    __syncthreads();

    const int m = lane & 15;
    const int chalf = (lane >> 4) & 1;
    const int half = lane >> 5;
    const int wbase = wave * 32;

    f32x4 acc[2][2][2] = {};                   // [row][mt][nt]
    const short8* wfv = (const short8*)wfrag;

    #pragma unroll
    for (int s = 0; s < KSTEPS; ++s) {
        const int t0 = 2 * s;
        const int t1 = (2 * s + 1 < 25) ? (2 * s + 1) : 24;  // pad tap -> tap 24
        const int kh0 = t0 / 5, kw0 = t0 % 5;
        const int kh1 = t1 / 5, kw1 = t1 % 5;
        const int kh = half ? kh1 : kh0;
        const int kw = half ? kw1 : kw0;
        short8 b0 = wfv[(s * 2 + 0) * 64 + lane];
        short8 b1 = wfv[(s * 2 + 1) * 64 + lane];
        #pragma unroll
        for (int r = 0; r < 2; ++r) {
            const int base = (((r + kh) * PW) + wbase + m + kw) * CIN + chalf * 8;
            short8 a0 = *(const short8*)&tile[base];
            short8 a1 = *(const short8*)&tile[base + 16 * CIN];
            acc[r][0][0] = __builtin_amdgcn_mfma_f32_16x16x32_bf16(a0, b0, acc[r][0][0], 0, 0, 0);
            acc[r][0][1] = __builtin_amdgcn_mfma_f32_16x16x32_bf16(a0, b1, acc[r][0][1], 0, 0, 0);
            acc[r][1][0] = __builtin_amdgcn_mfma_f32_16x16x32_bf16(a1, b0, acc[r][1][0], 0, 0, 0);
            acc[r][1][1] = __builtin_amdgcn_mfma_f32_16x16x32_bf16(a1, b1, acc[r][1][1], 0, 0, 0);
        }
    }

    // epilogue: D col = branch (lane&15), row = pixel (lane>>4)*4 + reg
    const int rowm = (lane >> 4) * 4;
    #pragma unroll
    for (int r = 0; r < 2; ++r) {
        const int hrow = h + r;
        #pragma unroll
        for (int nt = 0; nt < 2; ++nt) {
            const int branch = nt * 16 + m;
            const float bias = bc[branch];
            #pragma unroll
            for (int mt = 0; mt < 2; ++mt) {
                const int w0c = wbase + mt * 16 + rowm;
                float4 o;
                o.x = __builtin_amdgcn_rcpf(1.0f + __expf(-(acc[r][mt][nt][0] + bias)));
                o.y = __builtin_amdgcn_rcpf(1.0f + __expf(-(acc[r][mt][nt][1] + bias)));
                o.z = __builtin_amdgcn_rcpf(1.0f + __expf(-(acc[r][mt][nt][2] + bias)));
                o.w = __builtin_amdgcn_rcpf(1.0f + __expf(-(acc[r][mt][nt][3] + bias)));
                *(float4*)(out + (((size_t)b * NBR + branch) * HH + hrow) * WW + w0c) = o;
            }
        }
    }
}

extern "C" void kernel_launch(void* const* d_in, const int* in_sizes, int n_in,
                              void* d_out, int out_size, void* d_ws, size_t ws_size,
                              hipStream_t stream) {
    const float* x  = (const float*)d_in[0];
    const float* Wc = (const float*)d_in[1];
    const float* bc = (const float*)d_in[2];
    float* out = (float*)d_out;

    short* wfrag = (short*)d_ws;                         // 26,624 B
    short* xT    = (short*)((char*)d_ws + 32768);        // 26,615,808 B

    prep_wfrag<<<26, 64, 0, stream>>>(Wc, wfrag);
    transpose_x<<<dim3(57, 16), 256, 0, stream>>>(x, xT);
    semiconv_main<<<dim3(112, 16), 448, 0, stream>>>(xT, wfrag, bc, out);
}